// Round 1
// baseline (369.951 us; speedup 1.0000x reference)
//
#include <hip/hip_runtime.h>

// RegionIntegrator: B=4, N_REG=225 (15x15 grid, step 32), C=16, RS=64, H=W=512.
// Scatter-add of overlapping regions + divide-by-count, inverted to a gather:
// each output pixel (y,x) is covered by i in [max(0,(y-32)>>5), min(14,y>>5)]
// (1 or 2 row-starts) x same for columns -> count in {1,2,4}, closed form.
// Each region element is read exactly once -> traffic = 236 MB read + 67 MB
// write, pure HBM-bound (~48 us roofline at 6.3 TB/s).

constexpr int NREG_DIM = 15;   // 15 starts per axis
constexpr int CH       = 16;
constexpr int RS       = 64;
constexpr int HW       = 512;
constexpr int NREG     = NREG_DIM * NREG_DIM;  // 225

__global__ __launch_bounds__(256) void region_gather_kernel(
    const float* __restrict__ regions, float* __restrict__ out)
{
    // tid layout: b[2] | c[4] | y[9] | xq[7]  (xq = x/4, lane-fastest -> coalesced)
    int tid = blockIdx.x * 256 + threadIdx.x;
    int xq = tid & 127;          // x / 4
    int x  = xq << 2;
    int y  = (tid >> 7) & 511;
    int c  = (tid >> 16) & 15;
    int b  = tid >> 20;

    // covering region-start indices along each axis (step=32, RS=64)
    int i_min = (y >= 32) ? ((y - 32) >> 5) : 0;
    int i_max = min(NREG_DIM - 1, y >> 5);
    int j_min = (x >= 32) ? ((x - 32) >> 5) : 0;
    int j_max = min(NREG_DIM - 1, x >> 5);

    float4 acc = make_float4(0.f, 0.f, 0.f, 0.f);
    for (int i = i_min; i <= i_max; ++i) {
        int dy = y - (i << 5);
        for (int j = j_min; j <= j_max; ++j) {
            int dx = x - (j << 5);                    // multiple of 4 -> aligned float4
            int n  = i * NREG_DIM + j;
            const float4 v = *reinterpret_cast<const float4*>(
                regions + (size_t)((b * NREG + n) * CH + c) * (RS * RS) + dy * RS + dx);
            acc.x += v.x; acc.y += v.y; acc.z += v.z; acc.w += v.w;
        }
    }
    // count in {1,2,4} -> inv is an exact power of two, matches reference exactly
    float inv = 1.0f / (float)((i_max - i_min + 1) * (j_max - j_min + 1));
    float4 r = make_float4(acc.x * inv, acc.y * inv, acc.z * inv, acc.w * inv);
    reinterpret_cast<float4*>(out)[tid] = r;
}

extern "C" void kernel_launch(void* const* d_in, const int* in_sizes, int n_in,
                              void* d_out, int out_size, void* d_ws, size_t ws_size,
                              hipStream_t stream) {
    const float* regions = (const float*)d_in[0];   // (4,225,16,64,64) f32
    // d_in[1] orig_x: values unused (shape only). d_in[2] positions: regular
    // grid, folded into closed-form index math above. d_in[3..6]: scalars.
    float* out = (float*)d_out;                     // (4,16,512,512) f32

    int total_f4 = 4 * CH * HW * (HW / 4);          // 4,194,304 threads
    region_gather_kernel<<<total_f4 / 256, 256, 0, stream>>>(regions, out);
}